// Round 1
// baseline (22331.830 us; speedup 1.0000x reference)
//
#include <hip/hip_runtime.h>

// Problem constants: B=8, Cin1=512, Cout=256, S=512, H=64 -> H2=128.
// Outputs: h [8,256,128,128] then rgb [8,3,128,128], fp32, concatenated.

__device__ __forceinline__ void up_taps(int g, int& lo, int& hi, float& wlo) {
  // bilinear 2x upsample, half-pixel centers, edge clamp (src size 64)
  int m = g >> 1;
  if (g & 1) { lo = m; hi = (m + 1 < 63) ? m + 1 : 63; wlo = 0.75f; }
  else       { lo = (m - 1 > 0) ? m - 1 : 0; hi = m;   wlo = 0.25f; }
}

__global__ __launch_bounds__(256) void prep_kernel(
    const float* __restrict__ w1, const float* __restrict__ w2,
    const float* __restrict__ mod1_w, const float* __restrict__ mod1_b,
    const float* __restrict__ mod2_w, const float* __restrict__ mod2_b,
    const float* __restrict__ mod3_w, const float* __restrict__ mod3_b,
    const float* __restrict__ conv1_w, const float* __restrict__ conv2_w,
    float* __restrict__ s1, float* __restrict__ s2, float* __restrict__ s3,
    float* __restrict__ wsq1, float* __restrict__ wsq2)
{
  const float inv_sqrt_s = 0.04419417382415922f; // 1/sqrt(512)
  int idx = blockIdx.x * 256 + threadIdx.x;
  if (idx < 4096) {                       // s1 [8,512]
    int b = idx >> 9, i = idx & 511;
    const float* sp = w1 + b * 512;
    const float* mp = mod1_w + i * 512;
    float a = 0.f;
    for (int k = 0; k < 512; ++k) a += sp[k] * mp[k];
    s1[idx] = a * inv_sqrt_s + mod1_b[i];
  } else if (idx < 6144) {                // s2 [8,256]
    int t = idx - 4096, b = t >> 8, i = t & 255;
    const float* sp = w2 + b * 512;
    const float* mp = mod2_w + i * 512;
    float a = 0.f;
    for (int k = 0; k < 512; ++k) a += sp[k] * mp[k];
    s2[t] = a * inv_sqrt_s + mod2_b[i];
  } else if (idx < 8192) {                // s3 [8,256]
    int t = idx - 6144, b = t >> 8, i = t & 255;
    const float* sp = w2 + b * 512;
    const float* mp = mod3_w + i * 512;
    float a = 0.f;
    for (int k = 0; k < 512; ++k) a += sp[k] * mp[k];
    s3[t] = a * inv_sqrt_s + mod3_b[i];
  } else if (idx < 8192 + 131072) {       // wsq1 [256,512] = sum_kl w^2
    int t = idx - 8192;
    const float* wp = conv1_w + t * 9;
    float a = 0.f;
    #pragma unroll
    for (int k = 0; k < 9; ++k) a += wp[k] * wp[k];
    wsq1[t] = a;
  } else if (idx < 8192 + 131072 + 65536) { // wsq2 [256,256]
    int t = idx - 139264;
    const float* wp = conv2_w + t * 9;
    float a = 0.f;
    #pragma unroll
    for (int k = 0; k < 9; ++k) a += wp[k] * wp[k];
    wsq2[t] = a;
  }
}

__global__ __launch_bounds__(256) void demod_kernel(
    const float* __restrict__ s1, const float* __restrict__ s2,
    const float* __restrict__ wsq1, const float* __restrict__ wsq2,
    float* __restrict__ d1s, float* __restrict__ d2s)
{
  int idx = blockIdx.x * 256 + threadIdx.x; // 0..4095
  if (idx < 2048) {
    int b = idx >> 8, o = idx & 255;
    const float sc = 0.014731391274719742f; // 1/sqrt(512*9)
    const float* sp = s1 + b * 512;
    const float* wp = wsq1 + o * 512;
    float a = 0.f;
    for (int i = 0; i < 512; ++i) { float s = sp[i]; a += wp[i] * s * s; }
    d1s[idx] = sc * rsqrtf(sc * sc * a + 1e-8f);
  } else {
    int t = idx - 2048, b = t >> 8, o = t & 255;
    const float sc = 0.020833333333333332f; // 1/48 = 1/sqrt(256*9)
    const float* sp = s2 + b * 256;
    const float* wp = wsq2 + o * 256;
    float a = 0.f;
    for (int i = 0; i < 256; ++i) { float s = sp[i]; a += wp[i] * s * s; }
    d2s[t] = sc * rsqrtf(sc * sc * a + 1e-8f);
  }
}

// Direct 3x3 conv, pad=1, optional fused bilinear-2x-upsample of the input,
// modulation folded into LDS staging, demod+noise+leakyReLU epilogue.
// Block: 32x32 output tile x 4 output channels; thread = 1 row x 4 cols.
template<int CIN, bool UP>
__global__ __launch_bounds__(256) void conv3x3_kernel(
    const float* __restrict__ xin,   // UP ? [8,CIN,64,64] : [8,CIN,128,128]
    const float* __restrict__ wconv, // [256,CIN,3,3]
    const float* __restrict__ style, // [8,CIN]
    const float* __restrict__ dmod,  // [8,256]  (scale * rsqrt(...))
    const float* __restrict__ noise, // [8,128,128]
    const float* __restrict__ nw,    // [1]
    float* __restrict__ out)         // [8,256,128,128]
{
  constexpr int CC = 4;
  constexpr int IN_HW = UP ? 64 : 128;
  __shared__ float tile[CC * 34 * 34];

  const int tid = threadIdx.x;
  const int ty = tid >> 3;              // 0..31
  const int tx = tid & 7;               // 0..7
  const int o_base = blockIdx.x * 4;    // 64 o-tiles (fastest -> L2 x-reuse)
  const int i0 = (blockIdx.y >> 2) * 32;
  const int j0 = (blockIdx.y & 3) * 32;
  const int b = blockIdx.z;

  float acc[4][4];
  #pragma unroll
  for (int o = 0; o < 4; ++o)
    #pragma unroll
    for (int q = 0; q < 4; ++q) acc[o][q] = 0.f;

  for (int c0 = 0; c0 < CIN; c0 += CC) {
    // ---- stage CC channels of modulated (upsampled, zero-padded) input ----
    for (int e = tid; e < CC * 34 * 34; e += 256) {
      int cc = e / (34 * 34);
      int r  = e - cc * (34 * 34);
      int lr = r / 34;
      int lc = r - lr * 34;
      int gr = i0 - 1 + lr, gc = j0 - 1 + lc;   // 128-res coords (conv pad space)
      float v = 0.f;
      if ((unsigned)gr < 128u && (unsigned)gc < 128u) {
        int c = c0 + cc;
        const float* xc = xin + (size_t)(b * CIN + c) * (IN_HW * IN_HW);
        if (UP) {
          int rlo, rhi, clo, chi; float wr, wc;
          up_taps(gr, rlo, rhi, wr);
          up_taps(gc, clo, chi, wc);
          float v00 = xc[rlo * 64 + clo], v01 = xc[rlo * 64 + chi];
          float v10 = xc[rhi * 64 + clo], v11 = xc[rhi * 64 + chi];
          float top = wc * v00 + (1.f - wc) * v01;
          float bot = wc * v10 + (1.f - wc) * v11;
          v = wr * top + (1.f - wr) * bot;
        } else {
          v = xc[gr * 128 + gc];
        }
        v *= style[b * CIN + c];
      }
      tile[e] = v;
    }
    __syncthreads();

    // ---- accumulate ----
    #pragma unroll
    for (int cc = 0; cc < CC; ++cc) {
      const float* t = tile + cc * (34 * 34);
      float xv[3][6];
      #pragma unroll
      for (int dy = 0; dy < 3; ++dy)
        #pragma unroll
        for (int dx = 0; dx < 6; ++dx)
          xv[dy][dx] = t[(ty + dy) * 34 + 4 * tx + dx];
      int c = c0 + cc;
      #pragma unroll
      for (int o = 0; o < 4; ++o) {
        const float* wp = wconv + (size_t)((o_base + o) * CIN + c) * 9;
        float w0 = wp[0], w1_ = wp[1], w2_ = wp[2],
              w3 = wp[3], w4  = wp[4], w5  = wp[5],
              w6 = wp[6], w7  = wp[7], w8  = wp[8];
        #pragma unroll
        for (int q = 0; q < 4; ++q) {
          acc[o][q] += w0 * xv[0][q] + w1_ * xv[0][q + 1] + w2_ * xv[0][q + 2]
                     + w3 * xv[1][q] + w4  * xv[1][q + 1] + w5  * xv[1][q + 2]
                     + w6 * xv[2][q] + w7  * xv[2][q + 1] + w8  * xv[2][q + 2];
        }
      }
    }
    __syncthreads();
  }

  // ---- epilogue: demod, noise, leaky relu ----
  const float nwv = nw[0];
  const int orow = i0 + ty;
  const int ocol = j0 + 4 * tx;
  float nz[4];
  #pragma unroll
  for (int q = 0; q < 4; ++q)
    nz[q] = nwv * noise[((size_t)b * 128 + orow) * 128 + ocol + q];
  #pragma unroll
  for (int o = 0; o < 4; ++o) {
    float dm = dmod[b * 256 + o_base + o];
    float* op = out + ((size_t)(b * 256 + o_base + o) * 128 + orow) * 128 + ocol;
    #pragma unroll
    for (int q = 0; q < 4; ++q) {
      float y = acc[o][q] * dm + nz[q];
      op[q] = (y > 0.f) ? y : 0.2f * y;
    }
  }
}

// 1x1 modulated conv (no demod) + bilinear-upsampled skip add.
__global__ __launch_bounds__(256) void rgb_kernel(
    const float* __restrict__ h2,    // [8,256,128,128] (d_out h region)
    const float* __restrict__ rgbw,  // [3,256]
    const float* __restrict__ s3,    // [8,256]
    const float* __restrict__ skip,  // [8,3,64,64]
    float* __restrict__ rgb)         // [8,3,128,128]
{
  __shared__ float coef[3 * 256];
  const int b = blockIdx.y;
  for (int e = threadIdx.x; e < 768; e += 256) {
    int p = e >> 8, c = e & 255;
    coef[e] = rgbw[p * 256 + c] * s3[b * 256 + c] * 0.0625f; // 1/sqrt(256)
  }
  __syncthreads();
  const int pix = blockIdx.x * 256 + threadIdx.x; // 0..16383
  const int i = pix >> 7, j = pix & 127;
  const float* hp = h2 + (size_t)b * 256 * 16384 + pix;
  float r0 = 0.f, r1 = 0.f, r2 = 0.f;
  for (int c = 0; c < 256; ++c) {
    float hv = hp[(size_t)c * 16384];
    r0 += coef[c] * hv;
    r1 += coef[256 + c] * hv;
    r2 += coef[512 + c] * hv;
  }
  int rlo, rhi, clo, chi; float wr, wc;
  up_taps(i, rlo, rhi, wr);
  up_taps(j, clo, chi, wc);
  float r[3] = {r0, r1, r2};
  #pragma unroll
  for (int p = 0; p < 3; ++p) {
    const float* sp = skip + (size_t)(b * 3 + p) * 4096;
    float top = wc * sp[rlo * 64 + clo] + (1.f - wc) * sp[rlo * 64 + chi];
    float bot = wc * sp[rhi * 64 + clo] + (1.f - wc) * sp[rhi * 64 + chi];
    float sv = wr * top + (1.f - wr) * bot;
    rgb[((size_t)(b * 3 + p) * 128 + i) * 128 + j] = r[p] + sv;
  }
}

extern "C" void kernel_launch(void* const* d_in, const int* in_sizes, int n_in,
                              void* d_out, int out_size, void* d_ws, size_t ws_size,
                              hipStream_t stream) {
  const float* x       = (const float*)d_in[0];
  const float* w1      = (const float*)d_in[1];
  const float* w2      = (const float*)d_in[2];
  const float* skip    = (const float*)d_in[3];
  const float* noise1  = (const float*)d_in[4];
  const float* noise2  = (const float*)d_in[5];
  const float* conv1_w = (const float*)d_in[6];
  const float* mod1_w  = (const float*)d_in[7];
  const float* mod1_b  = (const float*)d_in[8];
  const float* conv2_w = (const float*)d_in[9];
  const float* mod2_w  = (const float*)d_in[10];
  const float* mod2_b  = (const float*)d_in[11];
  const float* rgb_w   = (const float*)d_in[12];
  const float* mod3_w  = (const float*)d_in[13];
  const float* mod3_b  = (const float*)d_in[14];
  const float* nw1     = (const float*)d_in[15];
  const float* nw2     = (const float*)d_in[16];

  float* ws   = (float*)d_ws;
  float* h1   = ws;                    // 8*256*128*128 = 33554432 floats
  float* s1   = h1 + 33554432;         // 4096
  float* s2   = s1 + 4096;             // 2048
  float* s3   = s2 + 2048;             // 2048
  float* d1s  = s3 + 2048;             // 2048
  float* d2s  = d1s + 2048;            // 2048
  float* wsq1 = d2s + 2048;            // 131072
  float* wsq2 = wsq1 + 131072;         // 65536   -> total ~135 MB

  float* hout   = (float*)d_out;           // [8,256,128,128]
  float* rgbout = hout + 33554432;         // [8,3,128,128]

  prep_kernel<<<800, 256, 0, stream>>>(w1, w2, mod1_w, mod1_b, mod2_w, mod2_b,
                                       mod3_w, mod3_b, conv1_w, conv2_w,
                                       s1, s2, s3, wsq1, wsq2);
  demod_kernel<<<16, 256, 0, stream>>>(s1, s2, wsq1, wsq2, d1s, d2s);
  conv3x3_kernel<512, true><<<dim3(64, 16, 8), 256, 0, stream>>>(
      x, conv1_w, s1, d1s, noise1, nw1, h1);
  conv3x3_kernel<256, false><<<dim3(64, 16, 8), 256, 0, stream>>>(
      h1, conv2_w, s2, d2s, noise2, nw2, hout);
  rgb_kernel<<<dim3(64, 8), 256, 0, stream>>>(hout, rgb_w, s3, skip, rgbout);
}

// Round 3
// 929.787 us; speedup vs baseline: 24.0182x; 24.0182x over previous
//
#include <hip/hip_runtime.h>

// B=8, Cin1=512, Cout=256, S=512, H=64 -> H2=128.
// Outputs: h [8,256,128,128] fp32 then rgb [8,3,128,128] fp32, concatenated.

typedef __attribute__((ext_vector_type(8))) short short8;
typedef __attribute__((ext_vector_type(4))) float floatx4;

__device__ __forceinline__ unsigned short f2bf(float f) {
  union { float f; unsigned int u; } c; c.f = f;
  unsigned int r = c.u + 0x7fffu + ((c.u >> 16) & 1u);
  return (unsigned short)(r >> 16);
}

__device__ __forceinline__ void up_taps(int g, int& lo, int& hi, float& wlo) {
  // bilinear 2x upsample, half-pixel centers, edge clamp (src size 64)
  int m = g >> 1;
  if (g & 1) { lo = m; hi = (m + 1 < 63) ? m + 1 : 63; wlo = 0.75f; }
  else       { lo = (m - 1 > 0) ? m - 1 : 0; hi = m;   wlo = 0.25f; }
}

// ---------------- small prep kernels (styles, demod, weights) ----------------

__global__ __launch_bounds__(256) void prep_kernel(
    const float* __restrict__ w1, const float* __restrict__ w2,
    const float* __restrict__ mod1_w, const float* __restrict__ mod1_b,
    const float* __restrict__ mod2_w, const float* __restrict__ mod2_b,
    const float* __restrict__ mod3_w, const float* __restrict__ mod3_b,
    const float* __restrict__ conv1_w, const float* __restrict__ conv2_w,
    float* __restrict__ s1, float* __restrict__ s2, float* __restrict__ s3,
    float* __restrict__ wsq1, float* __restrict__ wsq2)
{
  const float inv_sqrt_s = 0.04419417382415922f; // 1/sqrt(512)
  int idx = blockIdx.x * 256 + threadIdx.x;
  if (idx < 4096) {                       // s1 [8,512]
    int b = idx >> 9, i = idx & 511;
    const float* sp = w1 + b * 512;
    const float* mp = mod1_w + i * 512;
    float a = 0.f;
    for (int k = 0; k < 512; ++k) a += sp[k] * mp[k];
    s1[idx] = a * inv_sqrt_s + mod1_b[i];
  } else if (idx < 6144) {                // s2 [8,256]
    int t = idx - 4096, b = t >> 8, i = t & 255;
    const float* sp = w2 + b * 512;
    const float* mp = mod2_w + i * 512;
    float a = 0.f;
    for (int k = 0; k < 512; ++k) a += sp[k] * mp[k];
    s2[t] = a * inv_sqrt_s + mod2_b[i];
  } else if (idx < 8192) {                // s3 [8,256]
    int t = idx - 6144, b = t >> 8, i = t & 255;
    const float* sp = w2 + b * 512;
    const float* mp = mod3_w + i * 512;
    float a = 0.f;
    for (int k = 0; k < 512; ++k) a += sp[k] * mp[k];
    s3[t] = a * inv_sqrt_s + mod3_b[i];
  } else if (idx < 8192 + 131072) {       // wsq1 [256,512] = sum_kl w^2
    int t = idx - 8192;
    const float* wp = conv1_w + (size_t)t * 9;
    float a = 0.f;
    #pragma unroll
    for (int k = 0; k < 9; ++k) a += wp[k] * wp[k];
    wsq1[t] = a;
  } else if (idx < 8192 + 131072 + 65536) { // wsq2 [256,256]
    int t = idx - 139264;
    const float* wp = conv2_w + (size_t)t * 9;
    float a = 0.f;
    #pragma unroll
    for (int k = 0; k < 9; ++k) a += wp[k] * wp[k];
    wsq2[t] = a;
  }
}

__global__ __launch_bounds__(256) void demod_kernel(
    const float* __restrict__ s1, const float* __restrict__ s2,
    const float* __restrict__ wsq1, const float* __restrict__ wsq2,
    float* __restrict__ d1s, float* __restrict__ d2s)
{
  int idx = blockIdx.x * 256 + threadIdx.x; // 0..4095
  if (idx < 2048) {
    int b = idx >> 8, o = idx & 255;
    const float sc = 0.014731391274719742f; // 1/sqrt(512*9)
    const float* sp = s1 + b * 512;
    const float* wp = wsq1 + o * 512;
    float a = 0.f;
    for (int i = 0; i < 512; ++i) { float s = sp[i]; a += wp[i] * s * s; }
    d1s[idx] = sc * rsqrtf(sc * sc * a + 1e-8f);
  } else {
    int t = idx - 2048, b = t >> 8, o = t & 255;
    const float sc = 0.020833333333333332f; // 1/sqrt(256*9)
    const float* sp = s2 + b * 256;
    const float* wp = wsq2 + o * 256;
    float a = 0.f;
    for (int i = 0; i < 256; ++i) { float s = sp[i]; a += wp[i] * s * s; }
    d2s[t] = sc * rsqrtf(sc * sc * a + 1e-8f);
  }
}

// weights fp32 [och][cin][3][3] -> bf16 [tap][och][cin]
template<int CIN>
__global__ __launch_bounds__(256) void wtr_kernel(
    const float* __restrict__ w, unsigned short* __restrict__ wt)
{
  int T = blockIdx.x * 256 + threadIdx.x;   // och*CIN + cin
  int och = T / CIN, cin = T - och * CIN;
  const float* src = w + (size_t)T * 9;
  #pragma unroll
  for (int t = 0; t < 9; ++t)
    wt[((size_t)t * 256 + och) * CIN + cin] = f2bf(src[t]);
}

// zero the 1-pixel halo ring of h1pad [8][8][130][130][32] bf16
__global__ __launch_bounds__(256) void ringzero_kernel(unsigned short* __restrict__ h1pad)
{
  int T = blockIdx.x * 256 + threadIdx.x;   // < 516*256 = 132096
  int q = T & 3;
  int t = T >> 2;            // < 33024
  int p = t % 516;
  int u = t / 516;           // < 64
  int cb = u & 7, b = u >> 3;
  int gr, gc;
  if (p < 130)      { gr = 0;       gc = p; }
  else if (p < 260) { gr = 129;     gc = p - 130; }
  else if (p < 388) { gr = p - 259; gc = 0; }
  else              { gr = p - 387; gc = 129; }
  int4 z = {};
  *(int4*)(h1pad + ((((size_t)b * 8 + cb) * 130 + gr) * 130 + gc) * 32 + q * 8) = z;
}

// x [8,512,64,64] fp32 NCHW -> modulated (s1), 2x-upsampled bf16 blocked
// xup [8][16][128][128][32]  (channel-block 32 innermost)
__global__ __launch_bounds__(256) void upmod_kernel(
    const float* __restrict__ x, const float* __restrict__ s1,
    unsigned short* __restrict__ xup)
{
  int T = blockIdx.x * 256 + threadIdx.x;  // 2^23 total
  int gc = T & 127;
  int q  = (T >> 7) & 3;
  int gr = (T >> 9) & 127;
  int cb = (T >> 16) & 15;
  int b  = T >> 20;
  int rlo, rhi, clo, chi; float wr, wc;
  up_taps(gr, rlo, rhi, wr);
  up_taps(gc, clo, chi, wc);
  const int c0 = cb * 32 + q * 8;
  const float* xp = x + ((size_t)b * 512 + c0) * 4096;
  unsigned short o8[8];
  #pragma unroll
  for (int j = 0; j < 8; ++j) {
    const float* p = xp + j * 4096;
    float v00 = p[rlo * 64 + clo], v01 = p[rlo * 64 + chi];
    float v10 = p[rhi * 64 + clo], v11 = p[rhi * 64 + chi];
    float v = wr * (wc * v00 + (1.f - wc) * v01)
            + (1.f - wr) * (wc * v10 + (1.f - wc) * v11);
    v *= s1[b * 512 + c0 + j];
    o8[j] = f2bf(v);
  }
  *(int4*)(xup + ((((size_t)b * 16 + cb) * 128 + gr) * 128 + gc) * 32 + q * 8) = *(int4*)o8;
}

// ---------------- bf16 MFMA implicit-GEMM 3x3 conv ----------------
// Block: 16x16 output pixels x 64 och, 4 waves; wave = 4 m-tiles (rows) x 4 n-tiles.
// A: [m=pixel-col (lane&15)][k=channel (quad*8+j)], B: [k][n=och (lane&15)],
// D: col(lane&15)=och, row(quad*4+reg)=pixel-col  (m89/m97/m120-verified layouts).
// OUTF32=false (conv1): writes bf16 ring-padded blocked h1pad PRE-MODULATED by
// ostyle (= s2), so conv2 consumes a ready-made modulated input.
template<int CIN, bool RING, bool OUTF32>
__global__ __launch_bounds__(256, 2) void conv3x3_mfma(
    const unsigned short* __restrict__ xin,  // blocked bf16: [b][CIN/32][IW][IW][32]
    const unsigned short* __restrict__ wtr,  // bf16 [9][256][CIN]
    const float* __restrict__ dmod,          // [8,256]
    const float* __restrict__ noise,         // [8,128,128]
    const float* __restrict__ nwp,           // [1]
    const float* __restrict__ ostyle,        // [8,256] next-conv input style (conv1 only)
    float* __restrict__ outN,                // fp32 NCHW [8,256,128,128] (conv2)
    unsigned short* __restrict__ outR)       // bf16 ring-blocked [8][8][130][130][32] (conv1)
{
  constexpr int CB = CIN / 32;
  __shared__ unsigned short ldsA[324 * 32];  // 18x18 halo tile x 32ch
  __shared__ unsigned short ldsB[576 * 32];  // 9 taps x 64 och x 32ch

  const int tid  = threadIdx.x;
  const int l15  = tid & 15;
  const int quad = (tid >> 4) & 3;
  const int wave = tid >> 6;
  const int och0 = blockIdx.x * 64;
  const int i0 = (blockIdx.y >> 3) * 16;
  const int j0 = (blockIdx.y & 7) * 16;
  const int b = blockIdx.z;

  floatx4 acc[4][4];
  #pragma unroll
  for (int mi = 0; mi < 4; ++mi)
    #pragma unroll
    for (int nt = 0; nt < 4; ++nt)
      acc[mi][nt] = (floatx4){0.f, 0.f, 0.f, 0.f};

  for (int cb = 0; cb < CB; ++cb) {
    __syncthreads();
    // ---- stage A: 18x18 positions x 32 ch ----
    for (int e = tid; e < 1296; e += 256) {
      int q = e & 3, pos = e >> 2;
      int lr = pos / 18, lc = pos - lr * 18;
      int4 v = {};
      if (RING) {
        size_t ga = ((((size_t)b * CB + cb) * 130 + (i0 + lr)) * 130 + (j0 + lc)) * 32 + q * 8;
        v = *(const int4*)(xin + ga);
      } else {
        int gr = i0 - 1 + lr, gc = j0 - 1 + lc;
        if ((unsigned)gr < 128u && (unsigned)gc < 128u) {
          size_t ga = ((((size_t)b * CB + cb) * 128 + gr) * 128 + gc) * 32 + q * 8;
          v = *(const int4*)(xin + ga);
        }
      }
      *(int4*)(ldsA + pos * 32 + q * 8) = v;
    }
    // ---- stage B: 9 taps x 64 och x 32 ch ----
    for (int e = tid; e < 2304; e += 256) {
      int q = e & 3, pos = e >> 2;         // pos = tap*64 + o
      int tap = pos >> 6, o = pos & 63;
      size_t ga = ((size_t)(tap * 256 + och0 + o)) * CIN + cb * 32 + q * 8;
      *(int4*)(ldsB + pos * 32 + q * 8) = *(const int4*)(wtr + ga);
    }
    __syncthreads();
    // ---- 9-tap MFMA accumulate ----
    #pragma unroll
    for (int tap = 0; tap < 9; ++tap) {
      const int dy = tap / 3, dx = tap - dy * 3;
      short8 bf[4];
      #pragma unroll
      for (int nt = 0; nt < 4; ++nt)
        bf[nt] = *(const short8*)(ldsB + (tap * 64 + nt * 16 + l15) * 32 + quad * 8);
      #pragma unroll
      for (int mi = 0; mi < 4; ++mi) {
        short8 af = *(const short8*)(ldsA + ((wave * 4 + mi + dy) * 18 + l15 + dx) * 32 + quad * 8);
        #pragma unroll
        for (int nt = 0; nt < 4; ++nt)
          acc[mi][nt] = __builtin_amdgcn_mfma_f32_16x16x32_bf16(af, bf[nt], acc[mi][nt], 0, 0, 0);
      }
    }
  }

  // ---- epilogue: demod + noise + leaky relu (+ next-conv style for conv1) ----
  const float nwv = nwp[0];
  #pragma unroll
  for (int mi = 0; mi < 4; ++mi) {
    const int gr = i0 + wave * 4 + mi;
    const floatx4 nz = *(const floatx4*)(noise + ((size_t)b * 128 + gr) * 128 + j0 + quad * 4);
    #pragma unroll
    for (int nt = 0; nt < 4; ++nt) {
      const int och = och0 + nt * 16 + l15;
      const float d = dmod[b * 256 + och];
      floatx4 v = acc[mi][nt];
      if (OUTF32) {
        floatx4 o;
        #pragma unroll
        for (int r = 0; r < 4; ++r) {
          float y = v[r] * d + nwv * nz[r];
          o[r] = (y > 0.f) ? y : 0.2f * y;
        }
        *(floatx4*)(outN + (((size_t)b * 256 + och) * 128 + gr) * 128 + j0 + quad * 4) = o;
      } else {
        const int cbo = och >> 5, cl = och & 31;
        const float os = ostyle[b * 256 + och];   // s2: pre-modulate conv2 input
        #pragma unroll
        for (int r = 0; r < 4; ++r) {
          float y = v[r] * d + nwv * nz[r];
          y = (y > 0.f) ? y : 0.2f * y;
          int gc = j0 + quad * 4 + r;
          outR[((((size_t)b * 8 + cbo) * 130 + gr + 1) * 130 + (gc + 1)) * 32 + cl] = f2bf(y * os);
        }
      }
    }
  }
}

// 1x1 modulated conv (no demod) + bilinear-upsampled skip add.
__global__ __launch_bounds__(256) void rgb_kernel(
    const float* __restrict__ h2,    // [8,256,128,128] fp32 (d_out h region)
    const float* __restrict__ rgbw,  // [3,256]
    const float* __restrict__ s3,    // [8,256]
    const float* __restrict__ skip,  // [8,3,64,64]
    float* __restrict__ rgb)         // [8,3,128,128]
{
  __shared__ float coef[3 * 256];
  const int b = blockIdx.y;
  for (int e = threadIdx.x; e < 768; e += 256) {
    int p = e >> 8, c = e & 255;
    coef[e] = rgbw[p * 256 + c] * s3[b * 256 + c] * 0.0625f; // 1/sqrt(256)
  }
  __syncthreads();
  const int pix = blockIdx.x * 256 + threadIdx.x; // 0..16383
  const int i = pix >> 7, j = pix & 127;
  const float* hp = h2 + (size_t)b * 256 * 16384 + pix;
  float r0 = 0.f, r1 = 0.f, r2 = 0.f;
  for (int c = 0; c < 256; ++c) {
    float hv = hp[(size_t)c * 16384];
    r0 += coef[c] * hv;
    r1 += coef[256 + c] * hv;
    r2 += coef[512 + c] * hv;
  }
  int rlo, rhi, clo, chi; float wr, wc;
  up_taps(i, rlo, rhi, wr);
  up_taps(j, clo, chi, wc);
  float r[3] = {r0, r1, r2};
  #pragma unroll
  for (int p = 0; p < 3; ++p) {
    const float* sp = skip + (size_t)(b * 3 + p) * 4096;
    float top = wc * sp[rlo * 64 + clo] + (1.f - wc) * sp[rlo * 64 + chi];
    float bot = wc * sp[rhi * 64 + clo] + (1.f - wc) * sp[rhi * 64 + chi];
    float sv = wr * top + (1.f - wr) * bot;
    rgb[((size_t)(b * 3 + p) * 128 + i) * 128 + j] = r[p] + sv;
  }
}

extern "C" void kernel_launch(void* const* d_in, const int* in_sizes, int n_in,
                              void* d_out, int out_size, void* d_ws, size_t ws_size,
                              hipStream_t stream) {
  const float* x       = (const float*)d_in[0];
  const float* w1      = (const float*)d_in[1];
  const float* w2      = (const float*)d_in[2];
  const float* skip    = (const float*)d_in[3];
  const float* noise1  = (const float*)d_in[4];
  const float* noise2  = (const float*)d_in[5];
  const float* conv1_w = (const float*)d_in[6];
  const float* mod1_w  = (const float*)d_in[7];
  const float* mod1_b  = (const float*)d_in[8];
  const float* conv2_w = (const float*)d_in[9];
  const float* mod2_w  = (const float*)d_in[10];
  const float* mod2_b  = (const float*)d_in[11];
  const float* rgb_w   = (const float*)d_in[12];
  const float* mod3_w  = (const float*)d_in[13];
  const float* mod3_b  = (const float*)d_in[14];
  const float* nw1     = (const float*)d_in[15];
  const float* nw2     = (const float*)d_in[16];

  // workspace: h1pad bf16 blocked + transformed weights + styles/demod
  unsigned short* h1pad = (unsigned short*)d_ws;        // 8*8*130*130*32 = 34,611,200
  unsigned short* wtr1  = h1pad + 34611200;             // 9*256*512 = 1,179,648
  unsigned short* wtr2  = wtr1 + 1179648;               // 9*256*256 = 589,824
  float* fws = (float*)(wtr2 + 589824);
  float* s1   = fws;                 // 4096
  float* s2   = s1 + 4096;           // 2048
  float* s3   = s2 + 2048;           // 2048
  float* d1s  = s3 + 2048;           // 2048
  float* d2s  = d1s + 2048;          // 2048
  float* wsq1 = d2s + 2048;          // 131072
  float* wsq2 = wsq1 + 131072;       // 65536

  // d_out: h fp32 region doubles as xup bf16 scratch (exactly 134.2 MB) until conv2 writes it
  unsigned short* xup = (unsigned short*)d_out;         // [8][16][128][128][32] bf16
  float* hout   = (float*)d_out;                        // [8,256,128,128] fp32
  float* rgbout = hout + 33554432;                      // [8,3,128,128] fp32

  prep_kernel<<<800, 256, 0, stream>>>(w1, w2, mod1_w, mod1_b, mod2_w, mod2_b,
                                       mod3_w, mod3_b, conv1_w, conv2_w,
                                       s1, s2, s3, wsq1, wsq2);
  demod_kernel<<<16, 256, 0, stream>>>(s1, s2, wsq1, wsq2, d1s, d2s);
  wtr_kernel<512><<<512, 256, 0, stream>>>(conv1_w, wtr1);
  wtr_kernel<256><<<256, 256, 0, stream>>>(conv2_w, wtr2);
  ringzero_kernel<<<516, 256, 0, stream>>>(h1pad);
  upmod_kernel<<<32768, 256, 0, stream>>>(x, s1, xup);
  conv3x3_mfma<512, false, false><<<dim3(4, 64, 8), 256, 0, stream>>>(
      xup, wtr1, d1s, noise1, nw1, s2, nullptr, h1pad);
  conv3x3_mfma<256, true, true><<<dim3(4, 64, 8), 256, 0, stream>>>(
      h1pad, wtr2, d2s, noise2, nw2, nullptr, hout, nullptr);
  rgb_kernel<<<dim3(64, 8), 256, 0, stream>>>(hout, rgb_w, s3, skip, rgbout);
}